// Round 2
// baseline (789.661 us; speedup 1.0000x reference)
//
#include <hip/hip_runtime.h>

#define VOCAB 400000
#define DIM   300
#define HID   32
#define NOUT  2
#define BATCH 16384
#define SEQ   50

#define NSLOT     8   // LDS ring slots per wave
#define LOOKAHEAD 6   // tokens issued ahead of consume
// vmcnt at consume of token s: issued = 2*(s+LOOKAHEAD), need tokens 0..s
// retired (2*(s+1) insts) -> allowed outstanding = 2*LOOKAHEAD - 2 = 10.

__device__ __forceinline__ void gload_lds16(const float* gsrc, float* ldst) {
    __builtin_amdgcn_global_load_lds(
        (const __attribute__((address_space(1))) void*)gsrc,
        (__attribute__((address_space(3))) void*)ldst, 16, 0, 0);
}

// K1: one wave per batch row. Gather via global_load_lds DMA ring:
// queue depth no longer costs dest VGPRs, so ~12 x 1KB loads stay in flight
// per wave (vs ~12 x 16B before) -> gather becomes HBM/L3-BW-bound instead of
// latency-bound. Counted vmcnt(10) in the main loop; single vmcnt(0) drain
// before the 6-token tail. Epilogue (verified in R1) unchanged; its pooled
// buffer reuses ring slot 0 (dead after the drain), keeping LDS at
// 4*8*1216 = 38,912 B/block -> 4 blocks/CU.
__global__ __launch_bounds__(256, 4) void dan_main(
    const int*   __restrict__ tokens,
    const float* __restrict__ emb,
    const float* __restrict__ Vw,
    const float* __restrict__ Vb,
    const float* __restrict__ Ww,
    const float* __restrict__ Wb,
    float*       __restrict__ logits)
{
    const int wave = threadIdx.x >> 6;
    const int lane = threadIdx.x & 63;
    const int row  = blockIdx.x * 4 + wave;   // grid exact: row < BATCH

    const int* toks = tokens + row * SEQ;
    const bool has1 = (lane < (DIM / 4 - 64));  // lanes 0..10 own dims 256..299

    // [wave][slot][304 floats]: slot stride 1216 B keeps 16B alignment.
    __shared__ float gbuf[4][NSLOT][304];

    // --- prologue: issue tokens 0..LOOKAHEAD-1 ---
    #pragma unroll
    for (int s = 0; s < LOOKAHEAD; ++s) {
        const int t = toks[s];                      // wave-uniform (s_load)
        const float* src = emb + (size_t)t * DIM;
        float* dst = &gbuf[wave][s][0];             // wave-uniform LDS base
        gload_lds16(src + 4 * lane, dst);           // lanes 0..63 -> 1024 B
        if (has1) gload_lds16(src + 4 * (64 + lane), dst + 256);  // tail 176 B
    }

    float4 acc0 = make_float4(0.f, 0.f, 0.f, 0.f);
    float4 acc1 = make_float4(0.f, 0.f, 0.f, 0.f);

    // --- main loop: consume s, issue s+LOOKAHEAD ---
    #pragma unroll 2
    for (int s = 0; s < SEQ - LOOKAHEAD; ++s) {
        asm volatile("s_waitcnt vmcnt(10)" ::: "memory");
        __builtin_amdgcn_sched_barrier(0);
        const float4* sf = (const float4*)&gbuf[wave][s & (NSLOT - 1)][0];
        float4 v0 = sf[lane];
        acc0.x += v0.x; acc0.y += v0.y; acc0.z += v0.z; acc0.w += v0.w;
        if (has1) {
            float4 v1 = sf[64 + lane];
            acc1.x += v1.x; acc1.y += v1.y; acc1.z += v1.z; acc1.w += v1.w;
        }
        // issue token s+LOOKAHEAD into slot (s+LOOKAHEAD)&7 (never a live slot)
        const int t = toks[s + LOOKAHEAD];
        const float* src = emb + (size_t)t * DIM;
        float* dst = &gbuf[wave][(s + LOOKAHEAD) & (NSLOT - 1)][0];
        gload_lds16(src + 4 * lane, dst);
        if (has1) gload_lds16(src + 4 * (64 + lane), dst + 256);
    }

    // --- tail: drain once, consume last LOOKAHEAD tokens ---
    asm volatile("s_waitcnt vmcnt(0)" ::: "memory");
    __builtin_amdgcn_sched_barrier(0);
    #pragma unroll
    for (int s = SEQ - LOOKAHEAD; s < SEQ; ++s) {
        const float4* sf = (const float4*)&gbuf[wave][s & (NSLOT - 1)][0];
        float4 v0 = sf[lane];
        acc0.x += v0.x; acc0.y += v0.y; acc0.z += v0.z; acc0.w += v0.w;
        if (has1) {
            float4 v1 = sf[64 + lane];
            acc1.x += v1.x; acc1.y += v1.y; acc1.z += v1.z; acc1.w += v1.w;
        }
    }

    const float inv = 1.0f / (float)SEQ;
    acc0.x *= inv; acc0.y *= inv; acc0.z *= inv; acc0.w *= inv;

    // Stage pooled[300] into ring slot 0 (dead now); per-wave private.
    float* pool = &gbuf[wave][0][0];
    *(float4*)&pool[4 * lane] = acc0;
    if (has1) {
        acc1.x *= inv; acc1.y *= inv; acc1.z *= inv; acc1.w *= inv;
        *(float4*)&pool[256 + 4 * lane] = acc1;
    }
    __syncthreads();

    // k = lane&31 hidden unit; half 0 -> dims 0..151, half 1 -> 152..299
    const int k    = lane & 31;
    const int half = lane >> 5;
    const int base = half ? 152 : 0;
    const float* __restrict__ vrow = Vw + k * DIM + base;
    const float* pw = pool + base;

    float p = 0.f;
    #pragma unroll
    for (int i = 0; i < 37; ++i) {
        float4 a = *(const float4*)(pw + 4 * i);        // LDS broadcast read
        float4 w = *(const float4*)(vrow + 4 * i);      // L1/L2-hot (38.4 KB)
        p += a.x * w.x + a.y * w.y + a.z * w.z + a.w * w.w;
    }
    if (!half) {  // extra float4: dims 148..151
        float4 a = *(const float4*)(pw + 148);
        float4 w = *(const float4*)(vrow + 148);
        p += a.x * w.x + a.y * w.y + a.z * w.z + a.w * w.w;
    }
    p += __shfl_xor(p, 32, 64);   // both halves hold the full dot for k

    float hv = fmaxf(p + Vb[k], 0.f);
    float g0 = hv * Ww[k];
    float g1 = hv * Ww[HID + k];
    #pragma unroll
    for (int m = 1; m < 32; m <<= 1) {
        g0 += __shfl_xor(g0, m, 64);
        g1 += __shfl_xor(g1, m, 64);
    }
    if (lane == 0) {
        logits[row * 2 + 0] = g0 + Wb[0];
        logits[row * 2 + 1] = g1 + Wb[1];
    }
}

// K2 (fused reduce + final): per-column (axis=0) max + log-sum-exp over 16384
// rows, then out[b][j] = logits[b][j] - c[j]. ~384 KB traffic, a few us.
__global__ __launch_bounds__(1024) void dan_reduce_final(
    const float* __restrict__ logits, float* __restrict__ out)
{
    __shared__ float r0[1024];
    __shared__ float r1[1024];
    const int tid = threadIdx.x;

    float m0 = -INFINITY, m1 = -INFINITY;
    for (int b = tid; b < BATCH; b += 1024) {
        m0 = fmaxf(m0, logits[b * 2 + 0]);
        m1 = fmaxf(m1, logits[b * 2 + 1]);
    }
    r0[tid] = m0; r1[tid] = m1;
    __syncthreads();
    for (int s = 512; s > 0; s >>= 1) {
        if (tid < s) {
            r0[tid] = fmaxf(r0[tid], r0[tid + s]);
            r1[tid] = fmaxf(r1[tid], r1[tid + s]);
        }
        __syncthreads();
    }
    m0 = r0[0]; m1 = r1[0];
    __syncthreads();

    float s0 = 0.f, s1 = 0.f;
    for (int b = tid; b < BATCH; b += 1024) {
        s0 += __expf(logits[b * 2 + 0] - m0);
        s1 += __expf(logits[b * 2 + 1] - m1);
    }
    r0[tid] = s0; r1[tid] = s1;
    __syncthreads();
    for (int s = 512; s > 0; s >>= 1) {
        if (tid < s) {
            r0[tid] += r0[tid + s];
            r1[tid] += r1[tid + s];
        }
        __syncthreads();
    }
    const float c0 = m0 + __logf(r0[0]);
    const float c1 = m1 + __logf(r1[0]);
    for (int i = tid; i < BATCH * NOUT; i += 1024) {
        out[i] = logits[i] - ((i & 1) ? c1 : c0);
    }
}

extern "C" void kernel_launch(void* const* d_in, const int* in_sizes, int n_in,
                              void* d_out, int out_size, void* d_ws, size_t ws_size,
                              hipStream_t stream) {
    const int*   tokens = (const int*)  d_in[0];
    const float* emb    = (const float*)d_in[1];
    const float* Vw     = (const float*)d_in[2];
    const float* Vb     = (const float*)d_in[3];
    const float* Ww     = (const float*)d_in[4];
    const float* Wb     = (const float*)d_in[5];
    float* out    = (float*)d_out;
    float* logits = (float*)d_ws;   // BATCH*NOUT floats = 128 KB

    dan_main        <<<BATCH / 4, 256, 0, stream>>>(tokens, emb, Vw, Vb, Ww, Wb, logits);
    dan_reduce_final<<<1, 1024, 0, stream>>>(logits, out);
}

// Round 3
// 743.410 us; speedup vs baseline: 1.0622x; 1.0622x over previous
//
#include <hip/hip_runtime.h>

#define VOCAB 400000
#define DIM   300
#define HID   32
#define NOUT  2
#define BATCH 16384
#define SEQ   50

// K1: one wave (64 lanes) per batch row — register gather (R1 structure,
// proven fastest; the R2 global_load_lds ring regressed 2x: it halved
// resident waves (LDS 38.9KB -> 4 blocks/CU) and serialized consumption on
// in-order vmcnt. For random gather the controlling variable is independent
// request streams = resident waves, so stay at 8 blocks/CU / 32 waves.)
//
// Phase 1 (gather): lane l owns float4 index l (dims 4l..4l+3); lanes 0..10
// also own float4 64+l (dims 256..299). 50 embedding rows accumulated in
// registers. unroll 10 widens the compiler's load-scheduling window within
// the VGPR<=64 budget; 32-bit byte offsets (t*1200 < 2^32) trim addr math.
//
// Phase 2 (matmul): pooled vector staged to per-wave LDS; one hidden unit per
// lane k=lane&31 over half the dims (152/148 split); 1 shfl_xor(32) merge +
// 10 shfl logit reduce. Verified in R1.
__global__ __launch_bounds__(256, 8) void dan_main(
    const int*   __restrict__ tokens,
    const float* __restrict__ emb,
    const float* __restrict__ Vw,
    const float* __restrict__ Vb,
    const float* __restrict__ Ww,
    const float* __restrict__ Wb,
    float*       __restrict__ logits)
{
    const int wave = threadIdx.x >> 6;
    const int lane = threadIdx.x & 63;
    const int row  = blockIdx.x * 4 + wave;   // grid exact: row < BATCH

    const int* toks = tokens + row * SEQ;
    const bool has1 = (lane < (DIM / 4 - 64));  // lanes 0..10 own dims 256..299

    float4 acc0 = make_float4(0.f, 0.f, 0.f, 0.f);
    float4 acc1 = make_float4(0.f, 0.f, 0.f, 0.f);

    #pragma unroll 10
    for (int s = 0; s < SEQ; ++s) {
        const unsigned off = (unsigned)toks[s] * (unsigned)DIM;  // 32-bit: 480MB table
        const float4* e = (const float4*)(emb + off);
        float4 v0 = e[lane];
        acc0.x += v0.x; acc0.y += v0.y; acc0.z += v0.z; acc0.w += v0.w;
        if (has1) {
            float4 v1 = e[64 + lane];
            acc1.x += v1.x; acc1.y += v1.y; acc1.z += v1.z; acc1.w += v1.w;
        }
    }
    const float inv = 1.0f / (float)SEQ;
    acc0.x *= inv; acc0.y *= inv; acc0.z *= inv; acc0.w *= inv;

    // Stage pooled[300] to LDS (per-wave slice; 1216 B each, 16B-aligned).
    __shared__ float pool[4][304];
    *(float4*)&pool[wave][4 * lane] = acc0;
    if (has1) {
        acc1.x *= inv; acc1.y *= inv; acc1.z *= inv; acc1.w *= inv;
        *(float4*)&pool[wave][256 + 4 * lane] = acc1;
    }
    __syncthreads();

    // k = lane&31 hidden unit; half 0 -> dims 0..151 (38 f4), half 1 -> 152..299 (37 f4)
    const int k    = lane & 31;
    const int half = lane >> 5;
    const int base = half ? 152 : 0;
    const float* __restrict__ vrow = Vw + k * DIM + base;   // 16B-aligned
    const float* pw = &pool[wave][base];

    float p = 0.f;
    #pragma unroll
    for (int i = 0; i < 37; ++i) {
        float4 a = *(const float4*)(pw + 4 * i);        // LDS broadcast read
        float4 w = *(const float4*)(vrow + 4 * i);      // L1/L2-hot (38.4 KB)
        p += a.x * w.x + a.y * w.y + a.z * w.z + a.w * w.w;
    }
    if (!half) {  // extra float4: dims 148..151
        float4 a = *(const float4*)(pw + 148);
        float4 w = *(const float4*)(vrow + 148);
        p += a.x * w.x + a.y * w.y + a.z * w.z + a.w * w.w;
    }
    p += __shfl_xor(p, 32, 64);   // both halves hold the full dot for k

    float hv = fmaxf(p + Vb[k], 0.f);
    float g0 = hv * Ww[k];
    float g1 = hv * Ww[HID + k];
    #pragma unroll
    for (int m = 1; m < 32; m <<= 1) {
        g0 += __shfl_xor(g0, m, 64);
        g1 += __shfl_xor(g1, m, 64);
    }
    if (lane == 0) {
        logits[row * 2 + 0] = g0 + Wb[0];
        logits[row * 2 + 1] = g1 + Wb[1];
    }
}

// K2 (fused reduce + final): per-column (axis=0) max + log-sum-exp over 16384
// rows, then out[b][j] = logits[b][j] - c[j]. ~384 KB traffic, a few us.
__global__ __launch_bounds__(1024) void dan_reduce_final(
    const float* __restrict__ logits, float* __restrict__ out)
{
    __shared__ float r0[1024];
    __shared__ float r1[1024];
    const int tid = threadIdx.x;

    float m0 = -INFINITY, m1 = -INFINITY;
    for (int b = tid; b < BATCH; b += 1024) {
        m0 = fmaxf(m0, logits[b * 2 + 0]);
        m1 = fmaxf(m1, logits[b * 2 + 1]);
    }
    r0[tid] = m0; r1[tid] = m1;
    __syncthreads();
    for (int s = 512; s > 0; s >>= 1) {
        if (tid < s) {
            r0[tid] = fmaxf(r0[tid], r0[tid + s]);
            r1[tid] = fmaxf(r1[tid], r1[tid + s]);
        }
        __syncthreads();
    }
    m0 = r0[0]; m1 = r1[0];
    __syncthreads();

    float s0 = 0.f, s1 = 0.f;
    for (int b = tid; b < BATCH; b += 1024) {
        s0 += __expf(logits[b * 2 + 0] - m0);
        s1 += __expf(logits[b * 2 + 1] - m1);
    }
    r0[tid] = s0; r1[tid] = s1;
    __syncthreads();
    for (int s = 512; s > 0; s >>= 1) {
        if (tid < s) {
            r0[tid] += r0[tid + s];
            r1[tid] += r1[tid + s];
        }
        __syncthreads();
    }
    const float c0 = m0 + __logf(r0[0]);
    const float c1 = m1 + __logf(r1[0]);
    for (int i = tid; i < BATCH * NOUT; i += 1024) {
        out[i] = logits[i] - ((i & 1) ? c1 : c0);
    }
}

extern "C" void kernel_launch(void* const* d_in, const int* in_sizes, int n_in,
                              void* d_out, int out_size, void* d_ws, size_t ws_size,
                              hipStream_t stream) {
    const int*   tokens = (const int*)  d_in[0];
    const float* emb    = (const float*)d_in[1];
    const float* Vw     = (const float*)d_in[2];
    const float* Vb     = (const float*)d_in[3];
    const float* Ww     = (const float*)d_in[4];
    const float* Wb     = (const float*)d_in[5];
    float* out    = (float*)d_out;
    float* logits = (float*)d_ws;   // BATCH*NOUT floats = 128 KB

    dan_main        <<<BATCH / 4, 256, 0, stream>>>(tokens, emb, Vw, Vb, Ww, Wb, logits);
    dan_reduce_final<<<1, 1024, 0, stream>>>(logits, out);
}